// Round 7
// baseline (27714.359 us; speedup 1.0000x reference)
//
#include <hip/hip_runtime.h>

#define LSEQ 8128
#define NB 8
#define CORR_CAP 8192
// uprod LDS geometry (unchanged)
#define HST 264
#define HROWS 9
#define HT1 (HROWS * HST)
// recur LDS geometry: local-half dbuf rows 9 x 136 shorts; per-wave remote
// stage regions 9 rows x 68 u32 words
#define HSTL 136
#define HTL (9 * HSTL)
#define RWR 68
#define RWW (9 * RWR)
#define RINGSZ 256
#define FLAG_R0A 0
#define FLAG_R0B 32
#define FLAG_R1A 64
#define FLAG_R1B 96
#define FLAG_H(q) (128 + (q) * 32)

typedef __attribute__((ext_vector_type(8))) short short8;
typedef __attribute__((ext_vector_type(4))) float float4e;
typedef unsigned long long ull;

#define MFMA16(a, b, c) __builtin_amdgcn_mfma_f32_16x16x32_bf16((a), (b), (c), 0, 0, 0)

// ---- workspace layout (bytes) ----
#define WS_P      4096ul
#define WS_AEE    528384ul
#define WS_VPN    536576ul      // bf16 [8128][1024]
#define WS_EIDX   17182720ul
#define WS_CORR   17444864ul    // bf16 [8192][1024]
#define WS_URING  34222080ul    // bf16 ring [256][8][1024] (4 MB)
#define WS_HX     38416384ul    // tagged h-exchange: 4 regions x 16 KB
#define WS_H0     42610688ul    // bf16 [8129][8][256]
#define WS_H1     75907072ul

static __device__ __forceinline__ unsigned short f2bf(float f) {
  unsigned u = __float_as_uint(f);
  return (unsigned short)((u + 0x7fffu + ((u >> 16) & 1u)) >> 16);  // RNE
}
static __device__ __forceinline__ float blo(unsigned u) { return __uint_as_float(u << 16); }
static __device__ __forceinline__ float bhi(unsigned u) { return __uint_as_float(u & 0xffff0000u); }
static __device__ __forceinline__ short8 pack8f(const float* __restrict__ p) {
  short8 r;
#pragma unroll
  for (int i = 0; i < 8; ++i) r[i] = (short)f2bf(p[i]);
  return r;
}
static __device__ __forceinline__ unsigned aload(const unsigned* p) {
  return __hip_atomic_load(p, __ATOMIC_RELAXED, __HIP_MEMORY_SCOPE_AGENT);
}
static __device__ __forceinline__ void astore(unsigned* p, unsigned v) {
  __hip_atomic_store(p, v, __ATOMIC_RELAXED, __HIP_MEMORY_SCOPE_AGENT);
}
static __device__ __forceinline__ ull aload64(const ull* p) {
  return __hip_atomic_load(p, __ATOMIC_RELAXED, __HIP_MEMORY_SCOPE_AGENT);
}
static __device__ __forceinline__ void astore64(ull* p, ull v) {
  __hip_atomic_store(p, v, __ATOMIC_RELAXED, __HIP_MEMORY_SCOPE_AGENT);
}
static __device__ __forceinline__ void fencev() {
  asm volatile("s_waitcnt vmcnt(0)" ::: "memory");
}
static __device__ __forceinline__ void drain8() {  // in-order retire: all but last 8 done
  asm volatile("s_waitcnt vmcnt(8)" ::: "memory");
}
static __device__ __forceinline__ void cbar() { asm volatile("" ::: "memory"); }
static __device__ __forceinline__ void barrier_lgkm() {
  asm volatile("s_waitcnt lgkmcnt(0)\ns_barrier" ::: "memory");
}
static __device__ __forceinline__ float sigf(float x) { return 1.f / (1.f + __expf(-x)); }
static __device__ __forceinline__ float tanhf2(float x) { return 2.f / (1.f + __expf(-2.f * x)) - 1.f; }

// ---- preps (unchanged) ----
__global__ void k_prep_P(const float* __restrict__ Wih0, const float* __restrict__ ewW2,
                         float* __restrict__ P) {
  int idx = blockIdx.x * 256 + threadIdx.x;
  int g = idx >> 7, k = idx & 127;
  const float* wr = Wih0 + (size_t)g * 320 + 128;
  float s = 0.f;
#pragma unroll 8
  for (int j = 0; j < 64; ++j) s += wr[j] * ewW2[j * 128 + k];
  P[idx] = s;
}

__global__ void k_prep_aee_init(const float* __restrict__ Wih0, const float* __restrict__ ee,
                                const float* __restrict__ b1, const float* __restrict__ b2,
                                const float* __restrict__ P, const float* __restrict__ inith,
                                float* __restrict__ aee, unsigned short* __restrict__ h0u,
                                unsigned short* __restrict__ h1u) {
  int idx = blockIdx.x * 256 + threadIdx.x;  // < 2048
  int s = idx >> 10, g = idx & 1023;
  const float* wr = Wih0 + (size_t)g * 320;
  float a = 0.f;
#pragma unroll 8
  for (int i = 0; i < 128; ++i) a += wr[i] * ee[s * 128 + i];
#pragma unroll 8
  for (int j = 0; j < 64; ++j) a += wr[128 + j] * b2[j];
  const float* pr = P + (size_t)g * 128;
#pragma unroll 8
  for (int k = 0; k < 128; ++k) a += pr[k] * fmaxf(b1[k], 0.f);
  aee[s * 1024 + g] = a;
  unsigned short hv = f2bf(inith[idx & 127]);
  h0u[idx] = hv;
  h1u[idx] = hv;
}

__global__ void k_prep_vpn(const float* __restrict__ Wih0, const float* __restrict__ nemb,
                           const float* __restrict__ aee, unsigned short* __restrict__ vpn) {
  __shared__ float pn[128];
  int t = blockIdx.x, tid = threadIdx.x;
  if (tid < 32) {
    float div = expf(-9.2103403719761836f * (float)(2 * tid) / 64.f);
    float ang = (float)t * div;
    pn[2 * tid] = sinf(ang);
    pn[2 * tid + 1] = cosf(ang);
  } else if (tid < 96) {
    int r = (int)((1.f + sqrtf(8.f * (float)t + 1.f)) * 0.5f);
    while (r * (r + 1) / 2 <= t) ++r;
    while (r * (r - 1) / 2 > t) --r;
    pn[64 + (tid - 32)] = nemb[r * 64 + (tid - 32)];
  }
  __syncthreads();
#pragma unroll
  for (int rr = 0; rr < 4; ++rr) {
    int row = rr * 256 + tid;
    const float* wr = Wih0 + (size_t)row * 320 + 192;
    float s = 0.f;
#pragma unroll 8
    for (int i = 0; i < 128; ++i) s += wr[i] * pn[i];
    vpn[(size_t)t * 1024 + row] = f2bf(s + aee[row]);
  }
}

__global__ void k_prep_eidx(const float* __restrict__ xadj, int* __restrict__ eidx,
                            unsigned* __restrict__ counter) {
  int idx = blockIdx.x * 256 + threadIdx.x;
  if (idx >= NB * LSEQ) return;
  int t = idx % LSEQ;
  int e = -1;
  if (t > 0 && xadj[idx - 1] > 0.f) {
    e = (int)atomicAdd(counter, 1u);
    if (e >= CORR_CAP) e = -1;
  }
  eidx[idx] = e;
}

__global__ void k_prep_corr(const float* __restrict__ xadj, const float* __restrict__ w1,
                            const float* __restrict__ b1, const float* __restrict__ P,
                            const float* __restrict__ aee, const int* __restrict__ eidx,
                            unsigned short* __restrict__ corr) {
  __shared__ float rh[128];
  int bid = blockIdx.x;
  int e = eidx[bid];
  if (e < 0) return;
  int tid = threadIdx.x;
  float wt = xadj[bid - 1];
  if (tid < 128) {
    float bb = b1[tid];
    rh[tid] = fmaxf(wt * w1[tid] + bb, 0.f) - fmaxf(bb, 0.f);
  }
  __syncthreads();
#pragma unroll
  for (int rr = 0; rr < 4; ++rr) {
    int row = rr * 256 + tid;
    const float* pr = P + (size_t)row * 128;
    float s = 0.f;
#pragma unroll 8
    for (int k = 0; k < 128; ++k) s += pr[k] * rh[k];
    corr[(size_t)e * 1024 + row] = f2bf(s + aee[1024 + row] - aee[row]);
  }
}

// ============ split-CU persistent recurrence (R6 + barrier-free staging) ============
// Per step: issue tagged poll sample (flies during X) -> L0 input loads ->
// X own-K MFMAs -> finish poll -> PER-WAVE stage of the full remote half
// into this wave's private LDS region (no cross-wave sync -> NO mid barrier)
// -> Z remote-K MFMAs -> 64-lane spread update -> ship-first epilogue ->
// ONE end barrier. Local hT half is double-buffered so X(t) (reads buf
// (t+1)&1) and update(t) (writes buf t&1) cannot race without the barrier.
template <int LAYER, int H>
static __device__ __forceinline__ void recur(
    const float* __restrict__ Wrec, const unsigned short* __restrict__ vpn,
    const int* __restrict__ eidx, const unsigned short* __restrict__ corr,
    const unsigned* __restrict__ uring, const float* __restrict__ inith,
    const float* __restrict__ initc, unsigned* flags, unsigned* hout,
    ull* hx, unsigned short* hT, unsigned* rws, int tid, int myflag) {
  const int wv = tid >> 6, l = tid & 63, lm = l & 15, lk = l >> 4;
  const int lmr = (lm < 8) ? lm : 8;   // lanes 8-15 broadcast the zero row (B operand)
  const int base = H * 128;
  const int rbase = 128 - base;
  const int bb = lm & 7;                   // owned batch
  const int hi = (lm >> 3) & 1;            // 0: j0,j1 ; 1: j2,j3 (update spread)
  const int jg = base + wv * 16 + lk * 4;  // wave's 4-col group (global j)
  const int jo = jg + hi * 2;              // this lane's 2 cols (global j)
  const int jl = jo - base;                // local col index
  unsigned budget = 20000000u;

  ull* hx_my = hx + (size_t)((LAYER * 2 + H) * 4) * 512;
  const ull* hx_rm = hx + (size_t)((LAYER * 2 + (1 - H)) * 4) * 512;
  const int widx = bb * 64 + wv * 8 + lk * 2 + hi;  // producer word (b*64 + jp)

  unsigned* rw = rws + wv * RWW;           // this wave's private remote stage
  const int sb = l >> 3;                   // staged batch row
  const int sj = (l & 7) * 8;              // staged jp start (8 words/lane)

  for (int i = tid; i < 2 * HTL; i += 512) hT[i] = 0;
  __syncthreads();
  {  // local init h -> buf1 (step 0 X reads buf[(0+1)&1] = buf1); row 8 zero
    int b = tid >> 6, c0 = (tid & 63) * 2;
    unsigned hv = (unsigned)f2bf(inith[(base + c0) & 127]) |
                  ((unsigned)f2bf(inith[(base + c0 + 1) & 127]) << 16);
    *(unsigned*)&hT[HTL + b * HSTL + c0] = hv;
  }
  // each wave fills its own remote-stage region with init remote half
  for (int i = l; i < RWW; i += 64) {
    int row = i / RWR, jp = i % RWR;
    unsigned v = 0u;
    if (row < 8 && jp < 64) {
      int c = jp * 2;
      v = (unsigned)f2bf(inith[(rbase + c) & 127]) |
          ((unsigned)f2bf(inith[(rbase + c + 1) & 127]) << 16);
    }
    rw[i] = v;
  }
  float cc[2];
  cc[0] = initc[jo & 127];
  cc[1] = initc[(jo + 1) & 127];

  // 4 gate-tiles, ALL K, register/AGPR-resident (gate-major rows g*256 + j)
  short8 wf[4][8];
#pragma unroll
  for (int g = 0; g < 4; ++g) {
    int row = g * 256 + base + wv * 16 + lm;
#pragma unroll
    for (int ks = 0; ks < 8; ++ks)
      wf[g][ks] = pack8f(Wrec + (size_t)row * 256 + ks * 32 + lk * 8);
  }
  __syncthreads();

  int e_nxt = (LAYER == 0) ? eidx[bb * LSEQ] : -1;
  unsigned Tm = 0;

  for (int t = 0; t < LSEQ; ++t) {
    const int rd = ((t + 1) & 1) * HTL;
    const int wr = (t & 1) * HTL;
    // ---- issue first poll sample EARLY (flies during X) ----
    ull q[8];
    const ull* ps = hx_rm + (size_t)(t & 3) * 512 + l * 8;
    if (t > 0) {
#pragma unroll
      for (int i = 0; i < 8; ++i) q[i] = aload64(ps + i);
    }
    // ---- L0 inputs (latency hides under X) ----
    unsigned vvs[4], cvs[4];
#pragma unroll
    for (int g = 0; g < 4; ++g) { vvs[g] = 0u; cvs[g] = 0u; }
    if (LAYER == 0) {
      const unsigned short* vp = vpn + (size_t)t * 1024;
#pragma unroll
      for (int g = 0; g < 4; ++g) vvs[g] = *(const unsigned*)(vp + g * 256 + jo);
      int e = e_nxt;
      if (t + 1 < LSEQ) e_nxt = eidx[bb * LSEQ + t + 1];
      if (e >= 0) {
        const unsigned short* cp = corr + (size_t)e * 1024;
#pragma unroll
        for (int g = 0; g < 4; ++g) cvs[g] = *(const unsigned*)(cp + g * 256 + jo);
      }
    }

    // ---- X: own-half K from local hT ----
    float4e acc[4];
#pragma unroll
    for (int g = 0; g < 4; ++g) acc[g] = (float4e){0.f, 0.f, 0.f, 0.f};
    __builtin_amdgcn_s_setprio(1);
#pragma unroll
    for (int ksl = 0; ksl < 4; ++ksl) {
      short8 hb = *(const short8*)(hT + rd + lmr * HSTL + ksl * 32 + lk * 8);
#pragma unroll
      for (int g = 0; g < 4; ++g) acc[g] = MFMA16(wf[g][H * 4 + ksl], hb, acc[g]);
    }
    __builtin_amdgcn_s_setprio(0);

    // ---- L1 ring inputs AFTER X (flag lag never blocks compute) ----
    if (LAYER == 1) {
      while (Tm < (unsigned)(t + 1)) {
        unsigned c0 = aload(flags + FLAG_H(0)), c1 = aload(flags + FLAG_H(1));
        unsigned c2 = aload(flags + FLAG_H(2)), c3 = aload(flags + FLAG_H(3));
        unsigned m0 = c0 < c1 ? c0 : c1, m1 = c2 < c3 ? c2 : c3;
        Tm = m0 < m1 ? m0 : m1;
        if (--budget == 0) break;
        asm volatile("s_sleep 1");
      }
      cbar();
      const unsigned* ub = uring + (size_t)(t & (RINGSZ - 1)) * 4096 + bb * 512;
#pragma unroll
      for (int g = 0; g < 4; ++g) vvs[g] = aload(ub + ((g * 256 + jo) >> 1));
    }

    // ---- finish poll; per-wave stage (NO cross-wave barrier) ----
    if (t > 0) {
      const unsigned tg = (unsigned)t;
      for (;;) {
        bool ok = true;
#pragma unroll
        for (int i = 0; i < 8; ++i) ok &= ((unsigned)(q[i] >> 32) == tg);
        if (ok || --budget == 0) break;
#pragma unroll
        for (int i = 0; i < 8; ++i) q[i] = aload64(ps + i);
      }
      cbar();
      uint4 w0, w1;
      w0.x = (unsigned)q[0]; w0.y = (unsigned)q[1]; w0.z = (unsigned)q[2]; w0.w = (unsigned)q[3];
      w1.x = (unsigned)q[4]; w1.y = (unsigned)q[5]; w1.z = (unsigned)q[6]; w1.w = (unsigned)q[7];
      *(uint4*)&rw[sb * RWR + sj] = w0;
      *(uint4*)&rw[sb * RWR + sj + 4] = w1;
    }

    // ---- Z: remote-half K from this wave's private stage ----
    __builtin_amdgcn_s_setprio(1);
#pragma unroll
    for (int ksl = 0; ksl < 4; ++ksl) {
      short8 hb = *(const short8*)(rw + lmr * RWR + ksl * 16 + lk * 4);
#pragma unroll
      for (int g = 0; g < 4; ++g) acc[g] = MFMA16(wf[g][(4 - H * 4) + ksl], hb, acc[g]);
    }
    __builtin_amdgcn_s_setprio(0);

    // ---- spread update over ALL 64 lanes; ship-first epilogue ----
    {
      float g0[4], g1[4];
#pragma unroll
      for (int g = 0; g < 4; ++g) {
        float s2 = __shfl_xor(acc[g][2], 8);
        float s3 = __shfl_xor(acc[g][3], 8);
        float a0 = hi ? s2 : acc[g][0];
        float a1 = hi ? s3 : acc[g][1];
        g0[g] = a0 + blo(vvs[g]) + (LAYER == 0 ? blo(cvs[g]) : 0.f);
        g1[g] = a1 + bhi(vvs[g]) + (LAYER == 0 ? bhi(cvs[g]) : 0.f);
      }
      float cn0 = sigf(g0[1]) * cc[0] + sigf(g0[0]) * tanhf2(g0[2]);
      float cn1 = sigf(g1[1]) * cc[1] + sigf(g1[0]) * tanhf2(g1[2]);
      cc[0] = cn0;
      cc[1] = cn1;
      float hv0 = sigf(g0[3]) * tanhf2(cn0);
      float hv1 = sigf(g1[3]) * tanhf2(cn1);
      unsigned hp = (unsigned)f2bf(hv0) | ((unsigned)f2bf(hv1) << 16);
      astore64(hx_my + (size_t)((t + 1) & 3) * 512 + widx,
               (ull)hp | (((ull)(unsigned)(t + 1)) << 32));      // ship FIRST (on chain)
      *(unsigned*)&hT[wr + bb * HSTL + jl] = hp;                 // local dbuf
      astore(hout + (size_t)(t + 1) * 1024 + bb * 128 + (jo >> 1), hp);
    }

    // ---- single end barrier; lagged unfenced flag publish ----
    if (LAYER == 0) {
      if ((t & 3) == 3) {
        if (t == LSEQ - 1) fencev(); else drain8();
      }
      barrier_lgkm();
      if ((t & 3) == 3 && tid == 0)
        astore(flags + myflag, (t == LSEQ - 1) ? (unsigned)LSEQ : (unsigned)t);
    } else {
      barrier_lgkm();
      if ((t & 63) == 63 && tid == 0) astore(flags + myflag, (unsigned)t);
    }
  }
}

// uprod quarter q (unchanged from R6).
static __device__ __forceinline__ void uprod(
    int q, const float* __restrict__ Wih1, unsigned* flags,
    const unsigned* __restrict__ h0w, unsigned* uring, unsigned short* hB, int tid) {
  const int wv = tid >> 6, l = tid & 63, lm = l & 15, lk = l >> 4;
  const int lmr = (lm < 8) ? lm : 8;
  unsigned budget = 20000000u;
  for (int i = tid; i < 2 * HT1; i += 512) hB[i] = 0;
  short8 wf[2][8];
#pragma unroll
  for (int tt = 0; tt < 2; ++tt) {
    int row = q * 256 + (wv * 2 + tt) * 16 + lm;
#pragma unroll
    for (int ks = 0; ks < 8; ++ks)
      wf[tt][ks] = pack8f(Wih1 + (size_t)row * 256 + ks * 32 + lk * 8);
  }
  __syncthreads();
  unsigned FcA = 0, FcB = 0, Fm = 0, PcA = 0, PcB = 0, Pm = 0;
  while (Fm < 2u) {
    FcA = aload(flags + FLAG_R0A);
    FcB = aload(flags + FLAG_R0B);
    Fm = FcA < FcB ? FcA : FcB;
    if (--budget == 0) break;
    asm volatile("s_sleep 1");
  }
  cbar();
  {
    uint2 t0 = ((const uint2*)(h0w + (size_t)1 * 1024))[tid];
    *(uint2*)((unsigned*)hB + wv * (HST / 2) + l * 2) = t0;
  }
  uint2 hw = ((const uint2*)(h0w + (size_t)2 * 1024))[tid];
  barrier_lgkm();
  for (int t = 0; t < LSEQ; ++t) {
    const int rdo = (t & 1) * HT1;
    const int wro = ((t + 1) & 1) * HT1;
    if (t + 1 < LSEQ)
      *(uint2*)((unsigned*)(hB + wro) + wv * (HST / 2) + l * 2) = hw;
    short8 bfr[8];
#pragma unroll
    for (int ks = 0; ks < 8; ++ks)
      bfr[ks] = *(const short8*)(hB + rdo + lmr * HST + ks * 32 + lk * 8);
    float4e a0 = {0.f, 0.f, 0.f, 0.f}, a1 = a0;
    __builtin_amdgcn_s_setprio(1);
#pragma unroll
    for (int ks = 0; ks < 8; ++ks) {
      a0 = MFMA16(wf[0][ks], bfr[ks], a0);
      a1 = MFMA16(wf[1][ks], bfr[ks], a1);
    }
    __builtin_amdgcn_s_setprio(0);
    int slot = t & (RINGSZ - 1);
    if (lm < 8) {
#pragma unroll
      for (int tt = 0; tt < 2; ++tt) {
        float4e a = tt ? a1 : a0;
        int g0 = q * 256 + (wv * 2 + tt) * 16 + lk * 4;
        unsigned p0 = (unsigned)f2bf(a[0]) | ((unsigned)f2bf(a[1]) << 16);
        unsigned p1 = (unsigned)f2bf(a[2]) | ((unsigned)f2bf(a[3]) << 16);
        unsigned* up = uring + (size_t)slot * 4096 + lm * 512 + (g0 >> 1);
        astore(up, p0);
        astore(up + 1, p1);
      }
    }
    if (t + 2 < LSEQ) {
      while (Fm < (unsigned)(t + 3)) {
        FcA = aload(flags + FLAG_R0A);
        FcB = aload(flags + FLAG_R0B);
        Fm = FcA < FcB ? FcA : FcB;
        if (--budget == 0) break;
        asm volatile("s_sleep 1");
      }
      while ((unsigned)(t + 1) >= Pm + 192u) {  // ring back-pressure (256 slots)
        PcA = aload(flags + FLAG_R1A);
        PcB = aload(flags + FLAG_R1B);
        Pm = PcA < PcB ? PcA : PcB;
        if (--budget == 0) break;
        asm volatile("s_sleep 1");
      }
      cbar();
      hw = ((const uint2*)(h0w + (size_t)(t + 3) * 1024))[tid];
    }
    if ((t & 7) == 7) {
      if (t == LSEQ - 1) fencev(); else drain8();
      barrier_lgkm();
      if (tid == 0)
        astore(flags + FLAG_H(q), (t == LSEQ - 1) ? (unsigned)LSEQ : (unsigned)(t - 1));
    } else {
      barrier_lgkm();
    }
  }
}

// grid=16: pairs on (0,8) / (1,9) target same-XCD under bx%8 round-robin
// (perf heuristic only; correctness is placement-independent).
__global__ __launch_bounds__(512, 2) void k_lstm(
    const float* __restrict__ Whh0, const float* __restrict__ Wih1,
    const float* __restrict__ Whh1, const unsigned short* __restrict__ vpn,
    const int* __restrict__ eidx, const unsigned short* __restrict__ corr,
    const float* __restrict__ inith, const float* __restrict__ initc,
    unsigned* flags, unsigned* uring, ull* hx, unsigned* h0w, unsigned* h1w) {
  // recur: hT dbuf 2*HTL shorts (4896 B) + rws 8*RWW words (19584 B) = 24480 B
  // uprod: hB 2*HT1 shorts (9504 B) — carved from the same block
  __shared__ __align__(16) unsigned smem[6120];
  const int tid = threadIdx.x;
  const int bx = blockIdx.x;
  unsigned short* hT = (unsigned short*)smem;
  unsigned* rws = smem + (2 * HTL) / 2;  // 2448 shorts = 1224 words
  if (bx == 0)
    recur<0, 0>(Whh0, vpn, eidx, corr, nullptr, inith, initc, flags, h0w, hx, hT, rws, tid, FLAG_R0A);
  else if (bx == 8)
    recur<0, 1>(Whh0, vpn, eidx, corr, nullptr, inith, initc, flags, h0w, hx, hT, rws, tid, FLAG_R0B);
  else if (bx == 1)
    recur<1, 0>(Whh1, nullptr, nullptr, nullptr, uring, inith, initc, flags, h1w, hx, hT, rws, tid, FLAG_R1A);
  else if (bx == 9)
    recur<1, 1>(Whh1, nullptr, nullptr, nullptr, uring, inith, initc, flags, h1w, hx, hT, rws, tid, FLAG_R1B);
  else if (bx >= 2 && bx <= 5)
    uprod(bx - 2, Wih1, flags, h0w, uring, (unsigned short*)smem, tid);
}

// ---- heads (unchanged) ----
__global__ __launch_bounds__(256, 2) void k_heads(
    const unsigned short* __restrict__ h1u, const float* __restrict__ xadj,
    const float* __restrict__ lgW1, const float* __restrict__ lgb1,
    const float* __restrict__ lgW2, const float* __restrict__ lgb2,
    const float* __restrict__ muW1, const float* __restrict__ mub1,
    const float* __restrict__ muW2, const float* __restrict__ mub2,
    const float* __restrict__ vaW1, const float* __restrict__ vab1,
    const float* __restrict__ vaW2, const float* __restrict__ vab2,
    float* dout) {
  __shared__ float vals[4][3][64];
  const int tid = threadIdx.x;
  const int v = tid >> 6, l = tid & 63, lm = l & 15, lk = l >> 4;
  const int wid = blockIdx.x * 4 + v;
  const int m0 = wid * 64;

  short8 afr[4][8];
#pragma unroll
  for (int tt = 0; tt < 4; ++tt)
#pragma unroll
    for (int ks = 0; ks < 8; ++ks)
      afr[tt][ks] = *(const short8*)(h1u + (size_t)(m0 + tt * 16 + lm) * 256 + 2048 + ks * 32 + lk * 8);

  const float* W1s[3] = {lgW1, muW1, vaW1};
  const float* b1s[3] = {lgb1, mub1, vab1};
  const float* W2s[3] = {lgW2, muW2, vaW2};

  for (int h = 0; h < 3; ++h) {
    float accr[4][4];
#pragma unroll
    for (int tt = 0; tt < 4; ++tt)
#pragma unroll
      for (int r = 0; r < 4; ++r) accr[tt][r] = 0.f;
    const float* W1p = W1s[h];
    const float* b1p = b1s[h];
    const float* W2p = W2s[h];
    for (int nt = 0; nt < 32; ++nt) {
      float4e c0 = {0.f, 0.f, 0.f, 0.f}, c1 = c0, c2 = c0, c3 = c0;
      const float* wp = W1p + (size_t)(nt * 16 + lm) * 256;
#pragma unroll
      for (int ks = 0; ks < 8; ++ks) {
        short8 bfr = pack8f(wp + ks * 32 + lk * 8);
        c0 = MFMA16(afr[0][ks], bfr, c0);
        c1 = MFMA16(afr[1][ks], bfr, c1);
        c2 = MFMA16(afr[2][ks], bfr, c2);
        c3 = MFMA16(afr[3][ks], bfr, c3);
      }
      float bias = b1p[nt * 16 + lm], w2v = W2p[nt * 16 + lm];
#pragma unroll
      for (int r = 0; r < 4; ++r) {
        accr[0][r] += fmaxf(c0[r] + bias, 0.f) * w2v;
        accr[1][r] += fmaxf(c1[r] + bias, 0.f) * w2v;
        accr[2][r] += fmaxf(c2[r] + bias, 0.f) * w2v;
        accr[3][r] += fmaxf(c3[r] + bias, 0.f) * w2v;
      }
    }
#pragma unroll
    for (int tt = 0; tt < 4; ++tt)
#pragma unroll
      for (int r = 0; r < 4; ++r) {
        float a2 = accr[tt][r];
        a2 += __shfl_xor(a2, 1);
        a2 += __shfl_xor(a2, 2);
        a2 += __shfl_xor(a2, 4);
        a2 += __shfl_xor(a2, 8);
        if (lm == 0) vals[v][h][tt * 16 + lk * 4 + r] = a2;
      }
  }
  __syncthreads();
  {
    int m = m0 + l;
    int tq = m >> 3, b = m & 7;
    float z = vals[v][0][l] + lgb2[0];
    float mu = vals[v][1][l] + mub2[0];
    float lv = vals[v][2][l] + vab2[0];
    float x = xadj[(size_t)b * LSEQ + tq];
    float xt = (x > 0.f) ? 1.f : 0.f;
    float lr = fmaxf(z, 0.f) - z * xt + log1pf(expf(-fabsf(z)));
    float lw = 0.f;
    if (x > 0.f) {
      float sm = (x > 20.f) ? x : logf(expm1f(fminf(x, 20.f)));
      float d = mu - sm;
      lw = 0.5f * (lv + d * d * expf(-lv));
    }
#pragma unroll
    for (int d2 = 1; d2 < 64; d2 <<= 1) {
      lr += __shfl_xor(lr, d2);
      lw += __shfl_xor(lw, d2);
    }
    if (l == 0) {
      atomicAdd(dout + 0, lr * (1.f / 1024.f));
      atomicAdd(dout + 1, lw * (1.f / 1024.f));
    }
  }
}

extern "C" void kernel_launch(void* const* d_in, const int* in_sizes, int n_in,
                              void* d_out, int out_size, void* d_ws, size_t ws_size,
                              hipStream_t stream) {
  const float* x_adj = (const float*)d_in[0];
  const float* ee    = (const float*)d_in[1];
  const float* nemb  = (const float*)d_in[2];
  const float* ewW1  = (const float*)d_in[3];
  const float* ewb1  = (const float*)d_in[4];
  const float* ewW2  = (const float*)d_in[5];
  const float* ewb2  = (const float*)d_in[6];
  const float* Wih0  = (const float*)d_in[7];
  const float* Whh0  = (const float*)d_in[8];
  const float* Wih1  = (const float*)d_in[9];
  const float* Whh1  = (const float*)d_in[10];
  const float* muW1  = (const float*)d_in[11];
  const float* mub1  = (const float*)d_in[12];
  const float* muW2  = (const float*)d_in[13];
  const float* mub2  = (const float*)d_in[14];
  const float* vaW1  = (const float*)d_in[15];
  const float* vab1  = (const float*)d_in[16];
  const float* vaW2  = (const float*)d_in[17];
  const float* vab2  = (const float*)d_in[18];
  const float* lgW1  = (const float*)d_in[19];
  const float* lgb1  = (const float*)d_in[20];
  const float* lgW2  = (const float*)d_in[21];
  const float* lgb2  = (const float*)d_in[22];
  const float* inith = (const float*)d_in[23];
  const float* initc = (const float*)d_in[24];

  char* wsb = (char*)d_ws;
  unsigned* flags      = (unsigned*)wsb;                 // dwords [0, 256)
  unsigned* counter    = (unsigned*)(wsb + 2048);
  float* P             = (float*)(wsb + WS_P);
  float* aee           = (float*)(wsb + WS_AEE);
  unsigned short* vpn  = (unsigned short*)(wsb + WS_VPN);
  int* eidx            = (int*)(wsb + WS_EIDX);
  unsigned short* corr = (unsigned short*)(wsb + WS_CORR);
  unsigned* uring      = (unsigned*)(wsb + WS_URING);
  ull* hx              = (ull*)(wsb + WS_HX);
  unsigned* h0w        = (unsigned*)(wsb + WS_H0);
  unsigned* h1w        = (unsigned*)(wsb + WS_H1);
  unsigned short* h0u  = (unsigned short*)(wsb + WS_H0);
  unsigned short* h1u  = (unsigned short*)(wsb + WS_H1);

  (void)in_sizes; (void)n_in; (void)ws_size;

  hipMemsetAsync(d_ws, 0, 4096, stream);
  hipMemsetAsync(wsb + WS_HX, 0, 65536, stream);   // zero tags in hx
  hipMemsetAsync(d_out, 0, (size_t)out_size * 4, stream);

  k_prep_P<<<512, 256, 0, stream>>>(Wih0, ewW2, P);
  k_prep_aee_init<<<8, 256, 0, stream>>>(Wih0, ee, ewb1, ewb2, P, inith, aee, h0u, h1u);
  k_prep_vpn<<<LSEQ, 256, 0, stream>>>(Wih0, nemb, aee, vpn);
  k_prep_eidx<<<(NB * LSEQ) / 256, 256, 0, stream>>>(x_adj, eidx, counter);
  k_prep_corr<<<NB * LSEQ, 256, 0, stream>>>(x_adj, ewW1, ewb1, P, aee, eidx, corr);
  k_lstm<<<16, 512, 0, stream>>>(Whh0, Wih1, Whh1, vpn, eidx, corr, inith, initc,
                                 flags, uring, hx, h0w, h1w);
  k_heads<<<254, 256, 0, stream>>>(h1u, x_adj, lgW1, lgb1, lgW2, lgb2,
                                   muW1, mub1, muW2, mub2, vaW1, vab1, vaW2, vab2,
                                   (float*)d_out);
}

// Round 8
// 16931.606 us; speedup vs baseline: 1.6368x; 1.6368x over previous
//
#include <hip/hip_runtime.h>

#define LSEQ 8128
#define NB 8
#define CORR_CAP 8192
#define HST 264          // hT row stride (shorts); 528 B spreads banks
#define HROWS 9          // 8 batch rows + 1 shared zero row (lm>=8 broadcast)
#define HT1 (HROWS * HST)
#define RINGSZ 256
// flag dword offsets (128B apart; counter at +2048)
#define FLAG_R0A 0
#define FLAG_R0B 32
#define FLAG_R1A 64
#define FLAG_R1B 96
#define FLAG_H(q) (128 + (q) * 32)

typedef __attribute__((ext_vector_type(8))) short short8;
typedef __attribute__((ext_vector_type(4))) float float4e;
typedef unsigned long long ull;

#define MFMA16(a, b, c) __builtin_amdgcn_mfma_f32_16x16x32_bf16((a), (b), (c), 0, 0, 0)

// ---- workspace layout (bytes) ----
#define WS_P      4096ul
#define WS_AEE    528384ul
#define WS_VPN    536576ul      // bf16 [8128][1024]
#define WS_EIDX   17182720ul
#define WS_CORR   17444864ul    // bf16 [8192][1024]
#define WS_URING  34222080ul    // bf16 ring [256][8][1024] (4 MB)
#define WS_HX     38416384ul    // tagged h-exchange: 4 regions x 16 KB = 64 KB
#define WS_H0     42610688ul    // bf16 [8129][8][256]
#define WS_H1     75907072ul

static __device__ __forceinline__ unsigned short f2bf(float f) {
  unsigned u = __float_as_uint(f);
  return (unsigned short)((u + 0x7fffu + ((u >> 16) & 1u)) >> 16);  // RNE
}
static __device__ __forceinline__ float blo(unsigned u) { return __uint_as_float(u << 16); }
static __device__ __forceinline__ float bhi(unsigned u) { return __uint_as_float(u & 0xffff0000u); }
static __device__ __forceinline__ short8 pack8f(const float* __restrict__ p) {
  short8 r;
#pragma unroll
  for (int i = 0; i < 8; ++i) r[i] = (short)f2bf(p[i]);
  return r;
}
static __device__ __forceinline__ unsigned aload(const unsigned* p) {
  return __hip_atomic_load(p, __ATOMIC_RELAXED, __HIP_MEMORY_SCOPE_AGENT);
}
static __device__ __forceinline__ void astore(unsigned* p, unsigned v) {
  __hip_atomic_store(p, v, __ATOMIC_RELAXED, __HIP_MEMORY_SCOPE_AGENT);
}
static __device__ __forceinline__ ull aload64(const ull* p) {
  return __hip_atomic_load(p, __ATOMIC_RELAXED, __HIP_MEMORY_SCOPE_AGENT);
}
static __device__ __forceinline__ void astore64(ull* p, ull v) {
  __hip_atomic_store(p, v, __ATOMIC_RELAXED, __HIP_MEMORY_SCOPE_AGENT);
}
static __device__ __forceinline__ void fencev() {
  asm volatile("s_waitcnt vmcnt(0)" ::: "memory");
}
static __device__ __forceinline__ void drain8() {  // in-order retire: all but last 8 done
  asm volatile("s_waitcnt vmcnt(8)" ::: "memory");
}
static __device__ __forceinline__ void cbar() { asm volatile("" ::: "memory"); }
static __device__ __forceinline__ void barrier_lgkm() {
  asm volatile("s_waitcnt lgkmcnt(0)\ns_barrier" ::: "memory");
}
static __device__ __forceinline__ float sigf(float x) { return 1.f / (1.f + __expf(-x)); }
static __device__ __forceinline__ float tanhf2(float x) { return 2.f / (1.f + __expf(-2.f * x)) - 1.f; }

// ---- preps (unchanged) ----
__global__ void k_prep_P(const float* __restrict__ Wih0, const float* __restrict__ ewW2,
                         float* __restrict__ P) {
  int idx = blockIdx.x * 256 + threadIdx.x;
  int g = idx >> 7, k = idx & 127;
  const float* wr = Wih0 + (size_t)g * 320 + 128;
  float s = 0.f;
#pragma unroll 8
  for (int j = 0; j < 64; ++j) s += wr[j] * ewW2[j * 128 + k];
  P[idx] = s;
}

__global__ void k_prep_aee_init(const float* __restrict__ Wih0, const float* __restrict__ ee,
                                const float* __restrict__ b1, const float* __restrict__ b2,
                                const float* __restrict__ P, const float* __restrict__ inith,
                                float* __restrict__ aee, unsigned short* __restrict__ h0u,
                                unsigned short* __restrict__ h1u) {
  int idx = blockIdx.x * 256 + threadIdx.x;  // < 2048
  int s = idx >> 10, g = idx & 1023;
  const float* wr = Wih0 + (size_t)g * 320;
  float a = 0.f;
#pragma unroll 8
  for (int i = 0; i < 128; ++i) a += wr[i] * ee[s * 128 + i];
#pragma unroll 8
  for (int j = 0; j < 64; ++j) a += wr[128 + j] * b2[j];
  const float* pr = P + (size_t)g * 128;
#pragma unroll 8
  for (int k = 0; k < 128; ++k) a += pr[k] * fmaxf(b1[k], 0.f);
  aee[s * 1024 + g] = a;
  unsigned short hv = f2bf(inith[idx & 127]);
  h0u[idx] = hv;
  h1u[idx] = hv;
}

__global__ void k_prep_vpn(const float* __restrict__ Wih0, const float* __restrict__ nemb,
                           const float* __restrict__ aee, unsigned short* __restrict__ vpn) {
  __shared__ float pn[128];
  int t = blockIdx.x, tid = threadIdx.x;
  if (tid < 32) {
    float div = expf(-9.2103403719761836f * (float)(2 * tid) / 64.f);
    float ang = (float)t * div;
    pn[2 * tid] = sinf(ang);
    pn[2 * tid + 1] = cosf(ang);
  } else if (tid < 96) {
    int r = (int)((1.f + sqrtf(8.f * (float)t + 1.f)) * 0.5f);
    while (r * (r + 1) / 2 <= t) ++r;
    while (r * (r - 1) / 2 > t) --r;
    pn[64 + (tid - 32)] = nemb[r * 64 + (tid - 32)];
  }
  __syncthreads();
#pragma unroll
  for (int rr = 0; rr < 4; ++rr) {
    int row = rr * 256 + tid;
    const float* wr = Wih0 + (size_t)row * 320 + 192;
    float s = 0.f;
#pragma unroll 8
    for (int i = 0; i < 128; ++i) s += wr[i] * pn[i];
    vpn[(size_t)t * 1024 + row] = f2bf(s + aee[row]);
  }
}

__global__ void k_prep_eidx(const float* __restrict__ xadj, int* __restrict__ eidx,
                            unsigned* __restrict__ counter) {
  int idx = blockIdx.x * 256 + threadIdx.x;
  if (idx >= NB * LSEQ) return;
  int t = idx % LSEQ;
  int e = -1;
  if (t > 0 && xadj[idx - 1] > 0.f) {
    e = (int)atomicAdd(counter, 1u);
    if (e >= CORR_CAP) e = -1;
  }
  eidx[idx] = e;
}

__global__ void k_prep_corr(const float* __restrict__ xadj, const float* __restrict__ w1,
                            const float* __restrict__ b1, const float* __restrict__ P,
                            const float* __restrict__ aee, const int* __restrict__ eidx,
                            unsigned short* __restrict__ corr) {
  __shared__ float rh[128];
  int bid = blockIdx.x;
  int e = eidx[bid];
  if (e < 0) return;
  int tid = threadIdx.x;
  float wt = xadj[bid - 1];
  if (tid < 128) {
    float bb = b1[tid];
    rh[tid] = fmaxf(wt * w1[tid] + bb, 0.f) - fmaxf(bb, 0.f);
  }
  __syncthreads();
#pragma unroll
  for (int rr = 0; rr < 4; ++rr) {
    int row = rr * 256 + tid;
    const float* pr = P + (size_t)row * 128;
    float s = 0.f;
#pragma unroll 8
    for (int k = 0; k < 128; ++k) s += pr[k] * rh[k];
    corr[(size_t)e * 1024 + row] = f2bf(s + aee[1024 + row] - aee[row]);
  }
}

// ============ split-CU persistent recurrence (R6 structure + early poll) ============
// Per step: ISSUE tagged poll sample (flies during X) -> L0 input loads ->
// X own-K MFMAs -> (L1 ring loads) -> finish poll (sample usually already
// valid: partner shipped half a step earlier) -> cooperative 1-word stage ->
// mid barrier -> Z remote-K MFMAs -> 64-lane spread update -> ship ->
// end barrier. Flags lagged+unfenced (in-order vmcnt retirement).
template <int LAYER, int H>
static __device__ __forceinline__ void recur(
    const float* __restrict__ Wrec, const unsigned short* __restrict__ vpn,
    const int* __restrict__ eidx, const unsigned short* __restrict__ corr,
    const unsigned* __restrict__ uring, const float* __restrict__ inith,
    const float* __restrict__ initc, unsigned* flags, unsigned* hout,
    ull* hx, unsigned short* hT, int tid, int myflag) {
  const int wv = tid >> 6, l = tid & 63, lm = l & 15, lk = l >> 4;
  const int lmr = (lm < 8) ? lm : 8;   // lanes 8-15 broadcast the zero row (B operand)
  const int base = H * 128;
  const int rbase = 128 - base;
  const int bb = lm & 7;                       // owned batch
  const int hi = (lm >> 3) & 1;                // 0: j0,j1 ; 1: j2,j3 (update spread)
  const int jg = base + wv * 16 + lk * 4;      // wave's 4-col group (global j)
  const int jo = jg + hi * 2;                  // this lane's 2 cols (global j)
  unsigned budget = 20000000u;

  ull* hx_my = hx + (size_t)((LAYER * 2 + H) * 4) * 512;
  const ull* hx_rm = hx + (size_t)((LAYER * 2 + (1 - H)) * 4) * 512;
  const int widx = bb * 64 + wv * 8 + lk * 2 + hi;  // producer word (all 512 lanes)
  const int fb = tid >> 6, fl = tid & 63;
  const int rmc = fb * 64 + fl;                // consumer word
  const int fj = rbase + fl * 2;               // staged remote cols (2 shorts)

  for (int i = tid; i < HT1; i += 512) hT[i] = 0;
  __syncthreads();
  {  // rows 0-7 = init h over all 256 global cols; row 8 stays zero
    int b = tid >> 6, j0i = (tid & 63) * 4;
    unsigned h01 = (unsigned)f2bf(inith[j0i & 127]) | ((unsigned)f2bf(inith[(j0i + 1) & 127]) << 16);
    unsigned h23 = (unsigned)f2bf(inith[(j0i + 2) & 127]) | ((unsigned)f2bf(inith[(j0i + 3) & 127]) << 16);
    *(uint2*)&hT[b * HST + j0i] = make_uint2(h01, h23);
  }
  float cc[2];
  cc[0] = initc[jo & 127];
  cc[1] = initc[(jo + 1) & 127];

  // 4 gate-tiles, ALL K, register/AGPR-resident (gate-major rows g*256 + j)
  short8 wf[4][8];
#pragma unroll
  for (int g = 0; g < 4; ++g) {
    int row = g * 256 + base + wv * 16 + lm;
#pragma unroll
    for (int ks = 0; ks < 8; ++ks)
      wf[g][ks] = pack8f(Wrec + (size_t)row * 256 + ks * 32 + lk * 8);
  }
  __syncthreads();

  int e_nxt = (LAYER == 0) ? eidx[bb * LSEQ] : -1;
  unsigned Tm = 0;

  for (int t = 0; t < LSEQ; ++t) {
    // ---- EARLY poll issue: sample flies during X ----
    ull q = 0;
    const ull* ps = hx_rm + (size_t)(t & 3) * 512 + rmc;
    if (t > 0) q = aload64(ps);

    unsigned vvs[4], cvs[4];
#pragma unroll
    for (int g = 0; g < 4; ++g) { vvs[g] = 0u; cvs[g] = 0u; }
    // ---- L0 inputs at top (latency hides under X): 4B per gate per lane ----
    if (LAYER == 0) {
      const unsigned short* vp = vpn + (size_t)t * 1024;
#pragma unroll
      for (int g = 0; g < 4; ++g) vvs[g] = *(const unsigned*)(vp + g * 256 + jo);
      int e = e_nxt;
      if (t + 1 < LSEQ) e_nxt = eidx[bb * LSEQ + t + 1];
      if (e >= 0) {
        const unsigned short* cp = corr + (size_t)e * 1024;
#pragma unroll
        for (int g = 0; g < 4; ++g) cvs[g] = *(const unsigned*)(cp + g * 256 + jo);
      }
    }

    // ---- X: own-half K (no external deps -> runs before any gating) ----
    float4e acc[4];
#pragma unroll
    for (int g = 0; g < 4; ++g) acc[g] = (float4e){0.f, 0.f, 0.f, 0.f};
    __builtin_amdgcn_s_setprio(1);
#pragma unroll
    for (int ksl = 0; ksl < 4; ++ksl) {
      const int ks = H * 4 + ksl;
      short8 hb = *(const short8*)(hT + lmr * HST + ks * 32 + lk * 8);
#pragma unroll
      for (int g = 0; g < 4; ++g) acc[g] = MFMA16(wf[g][ks], hb, acc[g]);
    }
    __builtin_amdgcn_s_setprio(0);

    // ---- L1 inputs AFTER X: flag lag never blocks compute ----
    if (LAYER == 1) {
      while (Tm < (unsigned)(t + 1)) {
        unsigned c0 = aload(flags + FLAG_H(0)), c1 = aload(flags + FLAG_H(1));
        unsigned c2 = aload(flags + FLAG_H(2)), c3 = aload(flags + FLAG_H(3));
        unsigned m0 = c0 < c1 ? c0 : c1, m1 = c2 < c3 ? c2 : c3;
        Tm = m0 < m1 ? m0 : m1;
        if (--budget == 0) break;
        asm volatile("s_sleep 1");
      }
      cbar();
      const unsigned* ub = uring + (size_t)(t & (RINGSZ - 1)) * 4096 + bb * 512;
#pragma unroll
      for (int g = 0; g < 4; ++g) vvs[g] = aload(ub + ((g * 256 + jo) >> 1));
    }

    // ---- finish poll (sample usually valid already); cooperative stage ----
    if (t > 0) {
      while ((unsigned)(q >> 32) != (unsigned)t && --budget) q = aload64(ps);
      cbar();
      *(unsigned*)&hT[fb * HST + fj] = (unsigned)q;
    }
    barrier_lgkm();

    // ---- Z: remote-half K ----
    __builtin_amdgcn_s_setprio(1);
#pragma unroll
    for (int ksl = 0; ksl < 4; ++ksl) {
      const int ks = (4 - H * 4) + ksl;
      short8 hb = *(const short8*)(hT + lmr * HST + ks * 32 + lk * 8);
#pragma unroll
      for (int g = 0; g < 4; ++g) acc[g] = MFMA16(wf[g][ks], hb, acc[g]);
    }
    __builtin_amdgcn_s_setprio(0);

    // ---- spread update over ALL 64 lanes: shfl r2,r3 to high half ----
    float g0[4], g1[4];
#pragma unroll
    for (int g = 0; g < 4; ++g) {
      float s2 = __shfl_xor(acc[g][2], 8);
      float s3 = __shfl_xor(acc[g][3], 8);
      float a0 = hi ? s2 : acc[g][0];
      float a1 = hi ? s3 : acc[g][1];
      g0[g] = a0 + blo(vvs[g]) + (LAYER == 0 ? blo(cvs[g]) : 0.f);
      g1[g] = a1 + bhi(vvs[g]) + (LAYER == 0 ? bhi(cvs[g]) : 0.f);
    }
    {
      float cn0 = sigf(g0[1]) * cc[0] + sigf(g0[0]) * tanhf2(g0[2]);
      float cn1 = sigf(g1[1]) * cc[1] + sigf(g1[0]) * tanhf2(g1[2]);
      cc[0] = cn0;
      cc[1] = cn1;
      float hv0 = sigf(g0[3]) * tanhf2(cn0);
      float hv1 = sigf(g1[3]) * tanhf2(cn1);
      unsigned hp = (unsigned)f2bf(hv0) | ((unsigned)f2bf(hv1) << 16);
      astore64(hx_my + (size_t)((t + 1) & 3) * 512 + widx,
               (ull)hp | (((ull)(unsigned)(t + 1)) << 32));      // ship FIRST (on chain)
      *(unsigned*)&hT[bb * HST + jo] = hp;  // own cols; disjoint from staged remote
      astore(hout + (size_t)(t + 1) * 1024 + bb * 128 + (jo >> 1), hp);
    }

    // ---- end barrier; LAGGED UNFENCED flag publish (final step full-fenced) ----
    if (LAYER == 0) {
      if ((t & 3) == 3) {
        if (t == LSEQ - 1) fencev(); else drain8();
      }
      barrier_lgkm();
      if ((t & 3) == 3 && tid == 0)
        astore(flags + myflag, (t == LSEQ - 1) ? (unsigned)LSEQ : (unsigned)t);
    } else {
      barrier_lgkm();
      if ((t & 63) == 63 && tid == 0) astore(flags + myflag, (unsigned)t);
    }
  }
}

// uprod quarter q (unchanged from R6).
static __device__ __forceinline__ void uprod(
    int q, const float* __restrict__ Wih1, unsigned* flags,
    const unsigned* __restrict__ h0w, unsigned* uring, unsigned short* hB, int tid) {
  const int wv = tid >> 6, l = tid & 63, lm = l & 15, lk = l >> 4;
  const int lmr = (lm < 8) ? lm : 8;
  unsigned budget = 20000000u;
  for (int i = tid; i < 2 * HT1; i += 512) hB[i] = 0;
  short8 wf[2][8];
#pragma unroll
  for (int tt = 0; tt < 2; ++tt) {
    int row = q * 256 + (wv * 2 + tt) * 16 + lm;
#pragma unroll
    for (int ks = 0; ks < 8; ++ks)
      wf[tt][ks] = pack8f(Wih1 + (size_t)row * 256 + ks * 32 + lk * 8);
  }
  __syncthreads();
  unsigned FcA = 0, FcB = 0, Fm = 0, PcA = 0, PcB = 0, Pm = 0;
  while (Fm < 2u) {
    FcA = aload(flags + FLAG_R0A);
    FcB = aload(flags + FLAG_R0B);
    Fm = FcA < FcB ? FcA : FcB;
    if (--budget == 0) break;
    asm volatile("s_sleep 1");
  }
  cbar();
  {
    uint2 t0 = ((const uint2*)(h0w + (size_t)1 * 1024))[tid];
    *(uint2*)((unsigned*)hB + wv * (HST / 2) + l * 2) = t0;
  }
  uint2 hw = ((const uint2*)(h0w + (size_t)2 * 1024))[tid];
  barrier_lgkm();
  for (int t = 0; t < LSEQ; ++t) {
    const int rdo = (t & 1) * HT1;
    const int wro = ((t + 1) & 1) * HT1;
    if (t + 1 < LSEQ)
      *(uint2*)((unsigned*)(hB + wro) + wv * (HST / 2) + l * 2) = hw;
    short8 bfr[8];
#pragma unroll
    for (int ks = 0; ks < 8; ++ks)
      bfr[ks] = *(const short8*)(hB + rdo + lmr * HST + ks * 32 + lk * 8);
    float4e a0 = {0.f, 0.f, 0.f, 0.f}, a1 = a0;
    __builtin_amdgcn_s_setprio(1);
#pragma unroll
    for (int ks = 0; ks < 8; ++ks) {
      a0 = MFMA16(wf[0][ks], bfr[ks], a0);
      a1 = MFMA16(wf[1][ks], bfr[ks], a1);
    }
    __builtin_amdgcn_s_setprio(0);
    int slot = t & (RINGSZ - 1);
    if (lm < 8) {
#pragma unroll
      for (int tt = 0; tt < 2; ++tt) {
        float4e a = tt ? a1 : a0;
        int g0 = q * 256 + (wv * 2 + tt) * 16 + lk * 4;
        unsigned p0 = (unsigned)f2bf(a[0]) | ((unsigned)f2bf(a[1]) << 16);
        unsigned p1 = (unsigned)f2bf(a[2]) | ((unsigned)f2bf(a[3]) << 16);
        unsigned* up = uring + (size_t)slot * 4096 + lm * 512 + (g0 >> 1);
        astore(up, p0);
        astore(up + 1, p1);
      }
    }
    if (t + 2 < LSEQ) {
      while (Fm < (unsigned)(t + 3)) {
        FcA = aload(flags + FLAG_R0A);
        FcB = aload(flags + FLAG_R0B);
        Fm = FcA < FcB ? FcA : FcB;
        if (--budget == 0) break;
        asm volatile("s_sleep 1");
      }
      while ((unsigned)(t + 1) >= Pm + 192u) {  // ring back-pressure (256 slots)
        PcA = aload(flags + FLAG_R1A);
        PcB = aload(flags + FLAG_R1B);
        Pm = PcA < PcB ? PcA : PcB;
        if (--budget == 0) break;
        asm volatile("s_sleep 1");
      }
      cbar();
      hw = ((const uint2*)(h0w + (size_t)(t + 3) * 1024))[tid];
    }
    if ((t & 7) == 7) {
      if (t == LSEQ - 1) fencev(); else drain8();
      barrier_lgkm();
      if (tid == 0)
        astore(flags + FLAG_H(q), (t == LSEQ - 1) ? (unsigned)LSEQ : (unsigned)(t - 1));
    } else {
      barrier_lgkm();
    }
  }
}

// grid=16: recur pairs on (0,8)/(1,9) -> same XCD under bx%8 round-robin
// (exchange resolves in shared L2; placement heuristic only, correctness
// is placement-independent). uprod on 2..5; 6,7,10..15 exit immediately.
__global__ __launch_bounds__(512, 2) void k_lstm(
    const float* __restrict__ Whh0, const float* __restrict__ Wih1,
    const float* __restrict__ Whh1, const unsigned short* __restrict__ vpn,
    const int* __restrict__ eidx, const unsigned short* __restrict__ corr,
    const float* __restrict__ inith, const float* __restrict__ initc,
    unsigned* flags, unsigned* uring, ull* hx, unsigned* h0w, unsigned* h1w) {
  __shared__ __align__(16) unsigned short hT[2 * HT1];  // 9504 B total LDS
  const int tid = threadIdx.x;
  const int bx = blockIdx.x;
  if (bx == 0)
    recur<0, 0>(Whh0, vpn, eidx, corr, nullptr, inith, initc, flags, h0w, hx, hT, tid, FLAG_R0A);
  else if (bx == 8)
    recur<0, 1>(Whh0, vpn, eidx, corr, nullptr, inith, initc, flags, h0w, hx, hT, tid, FLAG_R0B);
  else if (bx == 1)
    recur<1, 0>(Whh1, nullptr, nullptr, nullptr, uring, inith, initc, flags, h1w, hx, hT, tid, FLAG_R1A);
  else if (bx == 9)
    recur<1, 1>(Whh1, nullptr, nullptr, nullptr, uring, inith, initc, flags, h1w, hx, hT, tid, FLAG_R1B);
  else if (bx >= 2 && bx <= 5)
    uprod(bx - 2, Wih1, flags, h0w, uring, hT, tid);
}

// ---- heads (unchanged) ----
__global__ __launch_bounds__(256, 2) void k_heads(
    const unsigned short* __restrict__ h1u, const float* __restrict__ xadj,
    const float* __restrict__ lgW1, const float* __restrict__ lgb1,
    const float* __restrict__ lgW2, const float* __restrict__ lgb2,
    const float* __restrict__ muW1, const float* __restrict__ mub1,
    const float* __restrict__ muW2, const float* __restrict__ mub2,
    const float* __restrict__ vaW1, const float* __restrict__ vab1,
    const float* __restrict__ vaW2, const float* __restrict__ vab2,
    float* dout) {
  __shared__ float vals[4][3][64];
  const int tid = threadIdx.x;
  const int v = tid >> 6, l = tid & 63, lm = l & 15, lk = l >> 4;
  const int wid = blockIdx.x * 4 + v;
  const int m0 = wid * 64;

  short8 afr[4][8];
#pragma unroll
  for (int tt = 0; tt < 4; ++tt)
#pragma unroll
    for (int ks = 0; ks < 8; ++ks)
      afr[tt][ks] = *(const short8*)(h1u + (size_t)(m0 + tt * 16 + lm) * 256 + 2048 + ks * 32 + lk * 8);

  const float* W1s[3] = {lgW1, muW1, vaW1};
  const float* b1s[3] = {lgb1, mub1, vab1};
  const float* W2s[3] = {lgW2, muW2, vaW2};

  for (int h = 0; h < 3; ++h) {
    float accr[4][4];
#pragma unroll
    for (int tt = 0; tt < 4; ++tt)
#pragma unroll
      for (int r = 0; r < 4; ++r) accr[tt][r] = 0.f;
    const float* W1p = W1s[h];
    const float* b1p = b1s[h];
    const float* W2p = W2s[h];
    for (int nt = 0; nt < 32; ++nt) {
      float4e c0 = {0.f, 0.f, 0.f, 0.f}, c1 = c0, c2 = c0, c3 = c0;
      const float* wp = W1p + (size_t)(nt * 16 + lm) * 256;
#pragma unroll
      for (int ks = 0; ks < 8; ++ks) {
        short8 bfr = pack8f(wp + ks * 32 + lk * 8);
        c0 = MFMA16(afr[0][ks], bfr, c0);
        c1 = MFMA16(afr[1][ks], bfr, c1);
        c2 = MFMA16(afr[2][ks], bfr, c2);
        c3 = MFMA16(afr[3][ks], bfr, c3);
      }
      float bias = b1p[nt * 16 + lm], w2v = W2p[nt * 16 + lm];
#pragma unroll
      for (int r = 0; r < 4; ++r) {
        accr[0][r] += fmaxf(c0[r] + bias, 0.f) * w2v;
        accr[1][r] += fmaxf(c1[r] + bias, 0.f) * w2v;
        accr[2][r] += fmaxf(c2[r] + bias, 0.f) * w2v;
        accr[3][r] += fmaxf(c3[r] + bias, 0.f) * w2v;
      }
    }
#pragma unroll
    for (int tt = 0; tt < 4; ++tt)
#pragma unroll
      for (int r = 0; r < 4; ++r) {
        float a2 = accr[tt][r];
        a2 += __shfl_xor(a2, 1);
        a2 += __shfl_xor(a2, 2);
        a2 += __shfl_xor(a2, 4);
        a2 += __shfl_xor(a2, 8);
        if (lm == 0) vals[v][h][tt * 16 + lk * 4 + r] = a2;
      }
  }
  __syncthreads();
  {
    int m = m0 + l;
    int tq = m >> 3, b = m & 7;
    float z = vals[v][0][l] + lgb2[0];
    float mu = vals[v][1][l] + mub2[0];
    float lv = vals[v][2][l] + vab2[0];
    float x = xadj[(size_t)b * LSEQ + tq];
    float xt = (x > 0.f) ? 1.f : 0.f;
    float lr = fmaxf(z, 0.f) - z * xt + log1pf(expf(-fabsf(z)));
    float lw = 0.f;
    if (x > 0.f) {
      float sm = (x > 20.f) ? x : logf(expm1f(fminf(x, 20.f)));
      float d = mu - sm;
      lw = 0.5f * (lv + d * d * expf(-lv));
    }
#pragma unroll
    for (int d2 = 1; d2 < 64; d2 <<= 1) {
      lr += __shfl_xor(lr, d2);
      lw += __shfl_xor(lw, d2);
    }
    if (l == 0) {
      atomicAdd(dout + 0, lr * (1.f / 1024.f));
      atomicAdd(dout + 1, lw * (1.f / 1024.f));
    }
  }
}

extern "C" void kernel_launch(void* const* d_in, const int* in_sizes, int n_in,
                              void* d_out, int out_size, void* d_ws, size_t ws_size,
                              hipStream_t stream) {
  const float* x_adj = (const float*)d_in[0];
  const float* ee    = (const float*)d_in[1];
  const float* nemb  = (const float*)d_in[2];
  const float* ewW1  = (const float*)d_in[3];
  const float* ewb1  = (const float*)d_in[4];
  const float* ewW2  = (const float*)d_in[5];
  const float* ewb2  = (const float*)d_in[6];
  const float* Wih0  = (const float*)d_in[7];
  const float* Whh0  = (const float*)d_in[8];
  const float* Wih1  = (const float*)d_in[9];
  const float* Whh1  = (const float*)d_in[10];
  const float* muW1  = (const float*)d_in[11];
  const float* mub1  = (const float*)d_in[12];
  const float* muW2  = (const float*)d_in[13];
  const float* mub2  = (const float*)d_in[14];
  const float* vaW1  = (const float*)d_in[15];
  const float* vab1  = (const float*)d_in[16];
  const float* vaW2  = (const float*)d_in[17];
  const float* vab2  = (const float*)d_in[18];
  const float* lgW1  = (const float*)d_in[19];
  const float* lgb1  = (const float*)d_in[20];
  const float* lgW2  = (const float*)d_in[21];
  const float* lgb2  = (const float*)d_in[22];
  const float* inith = (const float*)d_in[23];
  const float* initc = (const float*)d_in[24];

  char* wsb = (char*)d_ws;
  unsigned* flags      = (unsigned*)wsb;                 // dwords [0, 256)
  unsigned* counter    = (unsigned*)(wsb + 2048);
  float* P             = (float*)(wsb + WS_P);
  float* aee           = (float*)(wsb + WS_AEE);
  unsigned short* vpn  = (unsigned short*)(wsb + WS_VPN);
  int* eidx            = (int*)(wsb + WS_EIDX);
  unsigned short* corr = (unsigned short*)(wsb + WS_CORR);
  unsigned* uring      = (unsigned*)(wsb + WS_URING);
  ull* hx              = (ull*)(wsb + WS_HX);
  unsigned* h0w        = (unsigned*)(wsb + WS_H0);
  unsigned* h1w        = (unsigned*)(wsb + WS_H1);
  unsigned short* h0u  = (unsigned short*)(wsb + WS_H0);
  unsigned short* h1u  = (unsigned short*)(wsb + WS_H1);

  (void)in_sizes; (void)n_in; (void)ws_size;

  hipMemsetAsync(d_ws, 0, 4096, stream);
  hipMemsetAsync(wsb + WS_HX, 0, 65536, stream);   // zero tags in hx
  hipMemsetAsync(d_out, 0, (size_t)out_size * 4, stream);

  k_prep_P<<<512, 256, 0, stream>>>(Wih0, ewW2, P);
  k_prep_aee_init<<<8, 256, 0, stream>>>(Wih0, ee, ewb1, ewb2, P, inith, aee, h0u, h1u);
  k_prep_vpn<<<LSEQ, 256, 0, stream>>>(Wih0, nemb, aee, vpn);
  k_prep_eidx<<<(NB * LSEQ) / 256, 256, 0, stream>>>(x_adj, eidx, counter);
  k_prep_corr<<<NB * LSEQ, 256, 0, stream>>>(x_adj, ewW1, ewb1, P, aee, eidx, corr);
  k_lstm<<<16, 512, 0, stream>>>(Whh0, Wih1, Whh1, vpn, eidx, corr, inith, initc,
                                 flags, uring, hx, h0w, h1w);
  k_heads<<<254, 256, 0, stream>>>(h1u, x_adj, lgW1, lgb1, lgW2, lgb2,
                                   muW1, mub1, muW2, mub2, vaW1, vab1, vaW2, vab2,
                                   (float*)d_out);
}